// Round 20
// baseline (180.414 us; speedup 1.0000x reference)
//
#include <hip/hip_runtime.h>
#include <stdint.h>

#define S_LEN 2048
#define BATCH 2
#define DM 768
#define NH 12
#define DKH 64
#define DFF 3072
#define MROWS (BATCH * S_LEN)  // 4096
#define NBH (BATCH * NH)       // 24

typedef short bf16x8 __attribute__((ext_vector_type(8)));
typedef float f32x4 __attribute__((ext_vector_type(4)));
typedef float f32x16 __attribute__((ext_vector_type(16)));

__device__ __forceinline__ unsigned short f2b(float f) {
    union { float f; unsigned u; } cv; cv.f = f;
    unsigned u = cv.u;
    unsigned r = (u + 0x7FFFu + ((u >> 16) & 1u)) >> 16;  // RNE
    return (unsigned short)r;
}

__device__ __forceinline__ float b2f(unsigned short u) {
    union { unsigned u; float f; } cv; cv.u = ((unsigned)u) << 16;
    return cv.f;
}

__device__ __forceinline__ void gload16(const void* g, void* l) {
    __builtin_amdgcn_global_load_lds(
        (const __attribute__((address_space(1))) unsigned int*)g,
        (__attribute__((address_space(3))) unsigned int*)l, 16, 0, 0);
}

__device__ __forceinline__ unsigned cvtpk(float lo, float hi) {
    unsigned r;
    asm("v_cvt_pk_bf16_f32 %0, %1, %2" : "=v"(r) : "v"(lo), "v"(hi));
    return r;
}
__device__ __forceinline__ void pswap(unsigned &a, unsigned &b) {
    asm("v_permlane32_swap_b32 %0, %1" : "+v"(a), "+v"(b));
}
__device__ __forceinline__ bf16x8 mkpa(unsigned w0, unsigned w1, unsigned w2, unsigned w3) {
    union { unsigned u[4]; bf16x8 h; } cv;
    cv.u[0] = w0; cv.u[1] = w1; cv.u[2] = w2; cv.u[3] = w3;
    return cv.h;
}

// ---------------- fused prep: x f32->bf16 convert + 6 weight transposes ----------------
__global__ __launch_bounds__(256) void prep_kernel(
    const float* __restrict__ x,
    const float* __restrict__ wq, const float* __restrict__ wk,
    const float* __restrict__ wv, const float* __restrict__ wo,
    const float* __restrict__ w1, const float* __restrict__ w2,
    unsigned short* __restrict__ x16, unsigned short* __restrict__ wqkv16,
    unsigned short* __restrict__ wo16, unsigned short* __restrict__ w116,
    unsigned short* __restrict__ w216) {
    const int t = threadIdx.x;
    int bid = blockIdx.x;
    if (bid < 3072) {
        const int i = bid * 256 + t;  // n4 = 786432
        float4 v = reinterpret_cast<const float4*>(x)[i];
        ushort4 o;
        o.x = f2b(v.x); o.y = f2b(v.y); o.z = f2b(v.z); o.w = f2b(v.w);
        reinterpret_cast<ushort4*>(x16)[i] = o;
        return;
    }
    bid -= 3072;
    const float* in; unsigned short* out; int R, C, bx, by;
    if (bid < 2304) {
        const int wsel = bid / 576, r = bid % 576;
        in = (wsel == 0) ? wq : (wsel == 1) ? wk : (wsel == 2) ? wv : wo;
        out = (wsel == 3) ? wo16 : wqkv16 + (size_t)wsel * DM * DM;
        R = DM; C = DM; bx = r % 24; by = r / 24;
    } else if (bid < 4608) {
        const int r = bid - 2304;
        in = w1; out = w116; R = DM; C = DFF; bx = r % 96; by = r / 96;
    } else {
        const int r = bid - 4608;
        in = w2; out = w216; R = DFF; C = DM; bx = r % 24; by = r / 24;
    }
    __shared__ float tile[32][33];
    const int c0 = bx * 32, r0 = by * 32;
    const int tx = t & 31, ty = t >> 5;
    #pragma unroll
    for (int i = ty; i < 32; i += 8)
        tile[i][tx] = in[(size_t)(r0 + i) * C + c0 + tx];
    __syncthreads();
    #pragma unroll
    for (int i = ty; i < 32; i += 8)
        out[(size_t)(c0 + i) * R + r0 + tx] = f2b(tile[tx][i]);
}

// ============ 256x192-tile GEMM, 8 waves, BK=64, dbuf LDS + counted vmcnt + T2 swizzle ============
// (r18 measured-best 2-phase structure; 8-phase was neutral.)
#define STG192(buf, kt)                                                                  \
    {                                                                                    \
        const char* ga = (const char*)(A + (size_t)bm * lda + koff + ((kt) << 6));       \
        const char* gb = (const char*)(Bt + (size_t)bn * ldb + koff + ((kt) << 6));      \
        char* la = (char*)Sh + (buf) * 57344 + t * 16;                                   \
        char* lb = (char*)Sh + (buf) * 57344 + 32768 + t * 16;                           \
        _Pragma("unroll")                                                                \
        for (int p = 0; p < 4; ++p)                                                      \
            gload16(ga + (size_t)(sr + p * 64) * la2 + scb_sw, la + p * 8192);           \
        _Pragma("unroll")                                                                \
        for (int p = 0; p < 3; ++p)                                                      \
            gload16(gb + (size_t)(sr + p * 64) * lb2 + scb_sw, lb + p * 8192);           \
    }

template <int EPI>
__global__ __launch_bounds__(512, 2) void gemm192(
    const unsigned short* __restrict__ A, int lda,
    const unsigned short* __restrict__ Bt, int ldb,
    const float* __restrict__ bias0, const float* __restrict__ bias1,
    const float* __restrict__ bias2,
    unsigned short* __restrict__ ob0, unsigned short* __restrict__ ob1,
    unsigned short* __restrict__ ob2, float* __restrict__ of,
    int M, int N, int Ksub, float qscale) {
    __shared__ __align__(16) unsigned short Sh[2 * 28672];  // 112 KB
    const int t = threadIdx.x;
    const int wave = t >> 6, lane = t & 63;
    const int wr = wave >> 2, wc = wave & 3;
    // T1 XCD-chunked remap on (x,y) linear id
    const int gx = gridDim.x;
    const int nl = gx * gridDim.y;
    const int lid = blockIdx.y * gx + blockIdx.x;
    const int logical = (lid & 7) * (nl >> 3) + (lid >> 3);
    const int bn = (logical % gx) * 192, bm = (logical / gx) * 256;
    const int koff = (EPI == 3) ? blockIdx.z * Ksub : 0;
    const int lr = lane & 15;
    const int lk8 = (lane >> 4) << 3;
    const int sr = t >> 3;
    const int scb = (t & 7) * 16;
    const int scb_sw = scb ^ ((sr & 7) << 4);  // pre-swizzled source column
    const int swr = (lr & 7) << 4;             // read-side XOR
    const size_t la2 = (size_t)lda * 2, lb2 = (size_t)ldb * 2;

    f32x4 acc[8][3];
    #pragma unroll
    for (int i = 0; i < 8; ++i)
        #pragma unroll
        for (int j = 0; j < 3; ++j) { f32x4 z = {0.f, 0.f, 0.f, 0.f}; acc[i][j] = z; }

    const int nkt = Ksub >> 6;
    STG192(0, 0)
    for (int kt = 0; kt < nkt; ++kt) {
        const int cur = kt & 1;
        if (kt + 1 < nkt) {
            STG192(cur ^ 1, kt + 1)
            asm volatile("s_waitcnt vmcnt(7)" ::: "memory");
        } else {
            asm volatile("s_waitcnt vmcnt(0)" ::: "memory");
        }
        __builtin_amdgcn_s_barrier();
        __builtin_amdgcn_sched_barrier(0);
        const char* Ab = (const char*)Sh + cur * 57344;
        const char* Bb = Ab + 32768;
        #pragma unroll
        for (int ks = 0; ks < 64; ks += 32) {
            const int cbsw = ((ks + lk8) * 2) ^ swr;
            bf16x8 af[8], bfv[3];
            #pragma unroll
            for (int i = 0; i < 8; ++i)
                af[i] = *reinterpret_cast<const bf16x8*>(Ab + (wr * 128 + i * 16 + lr) * 128 + cbsw);
            #pragma unroll
            for (int j = 0; j < 3; ++j)
                bfv[j] = *reinterpret_cast<const bf16x8*>(Bb + (wc * 48 + j * 16 + lr) * 128 + cbsw);
            __builtin_amdgcn_s_setprio(1);
            #pragma unroll
            for (int i = 0; i < 8; ++i)
                #pragma unroll
                for (int j = 0; j < 3; ++j)
                    acc[i][j] = __builtin_amdgcn_mfma_f32_16x16x32_bf16(af[i], bfv[j], acc[i][j], 0, 0, 0);
            __builtin_amdgcn_s_setprio(0);
        }
        __builtin_amdgcn_s_barrier();
    }

    const int r0 = (lane >> 4) << 2;
    if (EPI == 0) {
        #pragma unroll
        for (int i = 0; i < 8; ++i) {
            const int row_b = bm + wr * 128 + i * 16 + r0;
            #pragma unroll
            for (int j = 0; j < 3; ++j) {
                const int col = bn + wc * 48 + j * 16 + lr;
                const float bvv = bias0[col];
                #pragma unroll
                for (int r = 0; r < 4; ++r) {
                    float vv = acc[i][j][r] + bvv;
                    vv = vv > 0.f ? vv : 0.f;
                    ob0[(size_t)(row_b + r) * N + col] = f2b(vv);
                }
            }
        }
    } else if (EPI == 1) {
        const int sec = (bn >= 2 * DM) ? 2 : (bn >= DM ? 1 : 0);
        const int nb = bn - sec * DM;
        const float* bias = (sec == 0) ? bias0 : (sec == 1 ? bias1 : bias2);
        #pragma unroll
        for (int i = 0; i < 8; ++i) {
            const int row_b = bm + wr * 128 + i * 16 + r0;
            const int b = row_b >> 11, s = row_b & 2047;
            #pragma unroll
            for (int j = 0; j < 3; ++j) {
                const int c768 = nb + wc * 48 + j * 16 + lr;
                const int h = c768 >> 6, d = c768 & 63;
                const float bvv = bias[c768];
                if (sec == 2) {
                    ushort4 w;
                    w.x = f2b(acc[i][j][0] + bvv);
                    w.y = f2b(acc[i][j][1] + bvv);
                    w.z = f2b(acc[i][j][2] + bvv);
                    w.w = f2b(acc[i][j][3] + bvv);
                    *reinterpret_cast<ushort4*>(
                        ob2 + (((size_t)(b * NH + h) * DKH) + d) * S_LEN + s) = w;
                } else {
                    const float sc = (sec == 0) ? qscale : 1.f;
                    unsigned short* dst = (sec == 0) ? ob0 : ob1;
                    #pragma unroll
                    for (int r = 0; r < 4; ++r)
                        dst[(((size_t)(b * NH + h) * S_LEN) + s + r) * DKH + d] =
                            f2b((acc[i][j][r] + bvv) * sc);
                }
            }
        }
    } else {  // EPI == 3: bf16 split-K partials
        unsigned short* op = ob0 + (size_t)blockIdx.z * M * N;
        #pragma unroll
        for (int i = 0; i < 8; ++i) {
            const int row_b = bm + wr * 128 + i * 16 + r0;
            #pragma unroll
            for (int j = 0; j < 3; ++j) {
                const int col = bn + wc * 48 + j * 16 + lr;
                #pragma unroll
                for (int r = 0; r < 4; ++r)
                    op[(size_t)(row_b + r) * N + col] = f2b(acc[i][j][r]);
            }
        }
    }
}

// ---------------- MFMA causal flash attention: 3-buf pipeline (QK(t+1) under softmax(t)) ----------------
#define STAGEKV(kt)                                                                   \
    {                                                                                 \
        char* bb = (char*)KV + ((kt) % 3) * 16384;                                    \
        const char* kg = kbyte + (((size_t)(kt)) << 13);                              \
        const char* vg = vbyte + (((size_t)(kt)) << 7);                               \
        char* lk = bb + lane * 16;                                                    \
        char* lv = bb + 8192 + lane * 16;                                             \
        _Pragma("unroll")                                                             \
        for (int i = 0; i < 8; ++i)                                                   \
            gload16(kg + (i * 8 + sub) * 128 + ccs, lk + i * 1024);                   \
        _Pragma("unroll")                                                             \
        for (int i = 0; i < 8; ++i)                                                   \
            gload16(vg + (size_t)(i * 8 + sub) * (S_LEN * 2) + ccs, lv + i * 1024);   \
    }

#define QKTILE(kt, d0, d1)                                                            \
    {                                                                                 \
        const char* Kb_ = (const char*)KV + ((kt) % 3) * 16384;                       \
        bf16x8 kaf[2][4];                                                             \
        _Pragma("unroll")                                                             \
        for (int kh = 0; kh < 2; ++kh)                                                \
            _Pragma("unroll")                                                         \
            for (int c = 0; c < 4; ++c)                                               \
                kaf[kh][c] = *reinterpret_cast<const bf16x8*>(                        \
                    Kb_ + (kh * 32 + x) * 128 + ((c * 32 + hi * 16) ^ swz));          \
        __builtin_amdgcn_s_setprio(1);                                                \
        _Pragma("unroll")                                                             \
        for (int c = 0; c < 4; ++c) {                                                 \
            d0 = __builtin_amdgcn_mfma_f32_32x32x16_bf16(kaf[0][c], qa[c], d0, 0, 0, 0); \
            d1 = __builtin_amdgcn_mfma_f32_32x32x16_bf16(kaf[1][c], qa[c], d1, 0, 0, 0); \
        }                                                                             \
        __builtin_amdgcn_s_setprio(0);                                                \
    }

__global__ __launch_bounds__(64) void attn_mfma_kernel(
    const unsigned short* __restrict__ q16,   // [B,H,S,64]
    const unsigned short* __restrict__ k16,   // [B,H,S,64]
    const unsigned short* __restrict__ vt16,  // [B,H,64,S]
    unsigned short* __restrict__ ctx16) {     // [B,S,DM]
    __shared__ __align__(16) char KV[3 * 16384];  // 48 KB: 3 bufs x (K 8K + V 8K)
    const int lane = threadIdx.x & 63;
    const int bh = blockIdx.x;
    const int qb = (gridDim.y - 1) - blockIdx.y;
    const int b = bh / NH, h = bh % NH;
    const size_t hbase = (size_t)bh * S_LEN * DKH;
    const int x = lane & 31;
    const int hi = lane >> 5;
    const int k8 = hi << 3;
    const int sW = qb << 5;
    const int qg = sW + x;
    const int sub = lane >> 3;
    const int ccs = ((lane & 7) * 16) ^ (sub << 4);
    const int swz = (x & 7) << 4;

    bf16x8 qa[4];
    #pragma unroll
    for (int c = 0; c < 4; ++c)
        qa[c] = *reinterpret_cast<const bf16x8*>(
            q16 + hbase + (size_t)(sW + x) * DKH + c * 16 + k8);

    float mst = -3e38f, lst = 0.f;
    f32x16 acc0, acc1;
    #pragma unroll
    for (int r = 0; r < 16; ++r) { acc0[r] = 0.f; acc1[r] = 0.f; }

    const char* kbyte = (const char*)(k16 + hbase);
    const char* vbyte = (const char*)(vt16 + hbase);
    const int nt = (sW >> 6) + 1;

    // prologue: stage(0) full-drain; stage(1) in flight; QK(0)
    STAGEKV(0)
    asm volatile("s_waitcnt vmcnt(0)" ::: "memory");
    if (nt > 1) STAGEKV(1)
    f32x16 sc0, sc1;
    #pragma unroll
    for (int r = 0; r < 16; ++r) { sc0[r] = 0.f; sc1[r] = 0.f; }
    QKTILE(0, sc0, sc1)

    for (int kt = 0; kt < nt; ++kt) {
        const int k0 = kt << 6;

        // --- wait K(kt+1) (counted: newest 8 = V-half may fly); stage(kt+2); QK(kt+1) ---
        // QK MFMAs then complete on the MFMA pipe underneath softmax(kt)'s VALU work.
        f32x16 sn0, sn1;
        #pragma unroll
        for (int r = 0; r < 16; ++r) { sn0[r] = 0.f; sn1[r] = 0.f; }
        if (kt + 1 < nt) {
            asm volatile("s_waitcnt vmcnt(8)" ::: "memory");
            if (kt + 2 < nt) STAGEKV(kt + 2)
            QKTILE(kt + 1, sn0, sn1)
        }

        // --- softmax(kt) on sc0/sc1 ---
        if (kt == nt - 1) {
            #pragma unroll
            for (int r = 0; r < 16; ++r) {
                const int cr = (r & 3) + (hi << 2) + ((r >> 2) << 3);
                if (k0 + cr > qg) sc0[r] = -3e38f;
                if (k0 + 32 + cr > qg) sc1[r] = -3e38f;
            }
        }

        float tm = fmaxf(sc0[0], sc0[1]);
        #pragma unroll
        for (int r = 2; r < 16; ++r) tm = fmaxf(tm, sc0[r]);
        #pragma unroll
        for (int r = 0; r < 16; ++r) tm = fmaxf(tm, sc1[r]);
        tm = fmaxf(tm, __shfl_xor(tm, 32));

        if (!__all(tm <= mst + 8.f)) {
            const float mn = fmaxf(mst, tm);
            const float corr = exp2f(mst - mn);
            mst = mn;
            lst *= corr;
            float cw[16];
            #pragma unroll
            for (int r = 0; r < 16; ++r)
                cw[r] = __shfl(corr, (r & 3) + (hi << 2) + ((r >> 2) << 3));
            #pragma unroll
            for (int r = 0; r < 16; ++r) { acc0[r] *= cw[r]; acc1[r] *= cw[r]; }
        }

        float ts = 0.f;
        #pragma unroll
        for (int r = 0; r < 16; ++r) {
            sc0[r] = exp2f(sc0[r] - mst); ts += sc0[r];
            sc1[r] = exp2f(sc1[r] - mst); ts += sc1[r];
        }
        ts += __shfl_xor(ts, 32);
        lst += ts;

        unsigned a0 = cvtpk(sc0[0], sc0[1]),   b0 = cvtpk(sc0[4], sc0[5]);   pswap(a0, b0);
        unsigned a1 = cvtpk(sc0[2], sc0[3]),   b1 = cvtpk(sc0[6], sc0[7]);   pswap(a1, b1);
        unsigned a2 = cvtpk(sc0[8], sc0[9]),   b2 = cvtpk(sc0[12], sc0[13]); pswap(a2, b2);
        unsigned a3 = cvtpk(sc0[10], sc0[11]), b3 = cvtpk(sc0[14], sc0[15]); pswap(a3, b3);
        bf16x8 pa00 = mkpa(a0, a1, b0, b1);
        bf16x8 pa01 = mkpa(a2, a3, b2, b3);
        unsigned c0 = cvtpk(sc1[0], sc1[1]),   d0 = cvtpk(sc1[4], sc1[5]);   pswap(c0, d0);
        unsigned c1 = cvtpk(sc1[2], sc1[3]),   d1 = cvtpk(sc1[6], sc1[7]);   pswap(c1, d1);
        unsigned c2 = cvtpk(sc1[8], sc1[9]),   d2 = cvtpk(sc1[12], sc1[13]); pswap(c2, d2);
        unsigned c3 = cvtpk(sc1[10], sc1[11]), d3 = cvtpk(sc1[14], sc1[15]); pswap(c3, d3);
        bf16x8 pa10 = mkpa(c0, c1, d0, d1);
        bf16x8 pa11 = mkpa(c2, c3, d2, d3);

        // --- PV(kt) from buf(kt%3) ---
        const char* Vb = (const char*)KV + (kt % 3) * 16384 + 8192;
        bf16x8 vaf[2][4];
        #pragma unroll
        for (int dt = 0; dt < 2; ++dt)
            #pragma unroll
            for (int s = 0; s < 4; ++s)
                vaf[dt][s] = *reinterpret_cast<const bf16x8*>(
                    Vb + (dt * 32 + x) * 128 + ((s * 32 + hi * 16) ^ swz));

        __builtin_amdgcn_s_setprio(1);
        acc0 = __builtin_amdgcn_mfma_f32_32x32x16_bf16(pa00, vaf[0][0], acc0, 0, 0, 0);
        acc1 = __builtin_amdgcn_mfma_f32_32x32x16_bf16(pa00, vaf[1][0], acc1, 0, 0, 0);
        acc0 = __builtin_amdgcn_mfma_f32_32x32x16_bf16(pa01, vaf[0][1], acc0, 0, 0, 0);
        acc1 = __builtin_amdgcn_mfma_f32_32x32x16_bf16(pa01, vaf[1][1], acc1, 0, 0, 0);
        acc0 = __builtin_amdgcn_mfma_f32_32x32x16_bf16(pa10, vaf[0][2], acc0, 0, 0, 0);
        acc1 = __builtin_amdgcn_mfma_f32_32x32x16_bf16(pa10, vaf[1][2], acc1, 0, 0, 0);
        acc0 = __builtin_amdgcn_mfma_f32_32x32x16_bf16(pa11, vaf[0][3], acc0, 0, 0, 0);
        acc1 = __builtin_amdgcn_mfma_f32_32x32x16_bf16(pa11, vaf[1][3], acc1, 0, 0, 0);
        __builtin_amdgcn_s_setprio(0);

        sc0 = sn0; sc1 = sn1;
    }

    const float li = 1.f / lst;
    float lw[16];
    #pragma unroll
    for (int r = 0; r < 16; ++r)
        lw[r] = __shfl(li, (r & 3) + (hi << 2) + ((r >> 2) << 3));
    #pragma unroll
    for (int r = 0; r < 16; ++r) {
        const int q = sW + (r & 3) + (hi << 2) + ((r >> 2) << 3);
        const size_t rowb = ((size_t)b * S_LEN + q) * DM + h * DKH;
        ctx16[rowb + x] = f2b(acc0[r] * lw[r]);
        ctx16[rowb + 32 + x] = f2b(acc1[r] * lw[r]);
    }
}

// ---------------- fused bf16-split-K merge + LayerNorm (192 thr/row) ----------------
template <int EB16OUT, int RES16>
__global__ __launch_bounds__(192) void ln_merge_kernel(
    const unsigned short* __restrict__ part, size_t pstride, int ns,
    const void* __restrict__ res, const float* __restrict__ bias,
    const float* __restrict__ gam, const float* __restrict__ bet,
    float* __restrict__ outf, unsigned short* __restrict__ outb) {
    __shared__ float red[8];
    const int row = blockIdx.x, t = threadIdx.x;
    const int wave = t >> 6, lane = t & 63;
    const size_t base = (size_t)row * DM;
    float4 v;
    if (RES16) {
        const ushort4 rv = reinterpret_cast<const ushort4*>((const unsigned short*)res + base)[t];
        v.x = b2f(rv.x); v.y = b2f(rv.y); v.z = b2f(rv.z); v.w = b2f(rv.w);
    } else {
        v = reinterpret_cast<const float4*>((const float*)res + base)[t];
    }
    const float4 bv = reinterpret_cast<const float4*>(bias)[t];
    v.x += bv.x; v.y += bv.y; v.z += bv.z; v.w += bv.w;
    for (int z = 0; z < ns; ++z) {
        const ushort4 p = reinterpret_cast<const ushort4*>(part + (size_t)z * pstride + base)[t];
        v.x += b2f(p.x); v.y += b2f(p.y); v.z += b2f(p.z); v.w += b2f(p.w);
    }
    float s = v.x + v.y + v.z + v.w;
    float sq = v.x * v.x + v.y * v.y + v.z * v.z + v.w * v.w;
    #pragma unroll
    for (int off = 32; off > 0; off >>= 1) { s += __shfl_xor(s, off); sq += __shfl_xor(sq, off); }
    if (lane == 0) { red[wave] = s; red[wave + 4] = sq; }
    __syncthreads();
    s = red[0] + red[1] + red[2];
    sq = red[4] + red[5] + red[6];
    const float mu = s * (1.f / DM);
    const float var = sq * (1.f / DM) - mu * mu;
    const float rs = rsqrtf(var + 1e-5f);
    const float4 g = reinterpret_cast<const float4*>(gam)[t];
    const float4 be = reinterpret_cast<const float4*>(bet)[t];
    float4 o;
    o.x = (v.x - mu) * rs * g.x + be.x;
    o.y = (v.y - mu) * rs * g.y + be.y;
    o.z = (v.z - mu) * rs * g.z + be.z;
    o.w = (v.w - mu) * rs * g.w + be.w;
    if (EB16OUT) {
        ushort4 ob;
        ob.x = f2b(o.x); ob.y = f2b(o.y); ob.z = f2b(o.z); ob.w = f2b(o.w);
        reinterpret_cast<ushort4*>(outb + base)[t] = ob;
    } else {
        reinterpret_cast<float4*>(outf + base)[t] = o;
    }
}

extern "C" void kernel_launch(void* const* d_in, const int* in_sizes, int n_in,
                              void* d_out, int out_size, void* d_ws, size_t ws_size,
                              hipStream_t stream) {
    const float* x   = (const float*)d_in[0];
    const float* wq  = (const float*)d_in[1];
    const float* bq  = (const float*)d_in[2];
    const float* wk  = (const float*)d_in[3];
    const float* bk  = (const float*)d_in[4];
    const float* wv  = (const float*)d_in[5];
    const float* bv  = (const float*)d_in[6];
    const float* wo  = (const float*)d_in[7];
    const float* bo  = (const float*)d_in[8];
    const float* w1  = (const float*)d_in[9];
    const float* b1  = (const float*)d_in[10];
    const float* w2  = (const float*)d_in[11];
    const float* b2  = (const float*)d_in[12];
    const float* g1  = (const float*)d_in[13];
    const float* be1 = (const float*)d_in[14];
    const float* g2  = (const float*)d_in[15];
    const float* be2 = (const float*)d_in[16];

    char* wp = (char*)d_ws;
    auto alloc = [&](size_t bytes) -> void* {
        void* r = (void*)wp;
        wp += (bytes + 255) & ~(size_t)255;
        return r;
    };
    const int M = MROWS;
    unsigned short* wqkv16 = (unsigned short*)alloc((size_t)3 * DM * DM * 2);  // [2304][768]
    unsigned short* wo16 = (unsigned short*)alloc((size_t)DM * DM * 2);
    unsigned short* w116 = (unsigned short*)alloc((size_t)DM * DFF * 2);
    unsigned short* w216 = (unsigned short*)alloc((size_t)DM * DFF * 2);
    unsigned short* ctx16 = (unsigned short*)alloc((size_t)M * DM * 2);
    unsigned short* x16  = (unsigned short*)alloc((size_t)M * DM * 2);
    unsigned short* q16  = (unsigned short*)alloc((size_t)M * DM * 2);
    unsigned short* k16  = (unsigned short*)alloc((size_t)M * DM * 2);
    unsigned short* vt16 = (unsigned short*)alloc((size_t)M * DM * 2);
    unsigned short* ff116 = x16;    // [M,DFF] bf16 over x16..vt16 (dead after attn)
    unsigned short* x116  = ctx16;  // LN1 bf16 output (ctx16 dead after WO gemm); also LN2 residual

    const size_t perb = (size_t)M * DM * 2;  // bf16 partial slice
    size_t used = (size_t)(wp - (char*)d_ws);
    int NS = 1;
    if (used + 4 * perb + 1024 <= ws_size) NS = 4;
    else if (used + 2 * perb + 1024 <= ws_size) NS = 2;
    unsigned short* part = (unsigned short*)alloc((size_t)NS * perb);
    const int NSW = (NS >= 2) ? 2 : 1;  // WO split-K factor

    prep_kernel<<<9984, 256, 0, stream>>>(x, wq, wk, wv, wo, w1, w2,
                                          x16, wqkv16, wo16, w116, w216);

    const float QSCALE = 0.125f * 1.44269504088896f;
    // QKV: 256x192 tile, N=2304 -> 12x16 = 192 blocks
    gemm192<1><<<dim3(3 * DM / 192, M / 256), 512, 0, stream>>>(
        x16, DM, wqkv16, DM, bq, bk, bv, q16, k16, vt16, nullptr, M, 3 * DM, DM, QSCALE);

    attn_mfma_kernel<<<dim3(NBH, S_LEN / 32), 64, 0, stream>>>(q16, k16, vt16, ctx16);

    // WO proj: split-K=NSW bf16 partials; LN1 = LN(sum + bo + x) -> x116 (bf16)
    gemm192<3><<<dim3(DM / 192, M / 256, NSW), 512, 0, stream>>>(
        ctx16, DM, wo16, DM, nullptr, nullptr, nullptr, part, nullptr, nullptr, nullptr,
        M, DM, DM / NSW, 1.f);
    ln_merge_kernel<1, 0><<<M, 192, 0, stream>>>(part, (size_t)M * DM, NSW, x, bo, g1, be1,
                                                 nullptr, x116);

    // FFN1: N=3072 -> 16x16 = 256 blocks (100% fill)
    gemm192<0><<<dim3(DFF / 192, M / 256), 512, 0, stream>>>(
        x116, DM, w116, DM, b1, nullptr, nullptr, ff116, nullptr, nullptr, nullptr, M, DFF, DM, 1.f);

    // FFN2: split-K=NS bf16 partials; LN2 = LN(sum + b2 + x116) -> d_out (f32)
    gemm192<3><<<dim3(DM / 192, M / 256, NS), 512, 0, stream>>>(
        ff116, DFF, w216, DFF, nullptr, nullptr, nullptr, part, nullptr, nullptr, nullptr,
        M, DM, DFF / NS, 1.f);
    ln_merge_kernel<0, 1><<<M, 192, 0, stream>>>(part, (size_t)M * DM, NS, x116, b2, g2, be2,
                                                 (float*)d_out, nullptr);
}

// Round 21
// 172.730 us; speedup vs baseline: 1.0445x; 1.0445x over previous
//
#include <hip/hip_runtime.h>
#include <stdint.h>

#define S_LEN 2048
#define BATCH 2
#define DM 768
#define NH 12
#define DKH 64
#define DFF 3072
#define MROWS (BATCH * S_LEN)  // 4096
#define NBH (BATCH * NH)       // 24

typedef short bf16x8 __attribute__((ext_vector_type(8)));
typedef float f32x4 __attribute__((ext_vector_type(4)));
typedef float f32x16 __attribute__((ext_vector_type(16)));

__device__ __forceinline__ unsigned short f2b(float f) {
    union { float f; unsigned u; } cv; cv.f = f;
    unsigned u = cv.u;
    unsigned r = (u + 0x7FFFu + ((u >> 16) & 1u)) >> 16;  // RNE
    return (unsigned short)r;
}

__device__ __forceinline__ float b2f(unsigned short u) {
    union { unsigned u; float f; } cv; cv.u = ((unsigned)u) << 16;
    return cv.f;
}

__device__ __forceinline__ void gload16(const void* g, void* l) {
    __builtin_amdgcn_global_load_lds(
        (const __attribute__((address_space(1))) unsigned int*)g,
        (__attribute__((address_space(3))) unsigned int*)l, 16, 0, 0);
}

__device__ __forceinline__ unsigned cvtpk(float lo, float hi) {
    unsigned r;
    asm("v_cvt_pk_bf16_f32 %0, %1, %2" : "=v"(r) : "v"(lo), "v"(hi));
    return r;
}
__device__ __forceinline__ void pswap(unsigned &a, unsigned &b) {
    asm("v_permlane32_swap_b32 %0, %1" : "+v"(a), "+v"(b));
}
__device__ __forceinline__ bf16x8 mkpa(unsigned w0, unsigned w1, unsigned w2, unsigned w3) {
    union { unsigned u[4]; bf16x8 h; } cv;
    cv.u[0] = w0; cv.u[1] = w1; cv.u[2] = w2; cv.u[3] = w3;
    return cv.h;
}

// ---------------- fused prep: x f32->bf16 convert + 6 weight transposes ----------------
__global__ __launch_bounds__(256) void prep_kernel(
    const float* __restrict__ x,
    const float* __restrict__ wq, const float* __restrict__ wk,
    const float* __restrict__ wv, const float* __restrict__ wo,
    const float* __restrict__ w1, const float* __restrict__ w2,
    unsigned short* __restrict__ x16, unsigned short* __restrict__ wqkv16,
    unsigned short* __restrict__ wo16, unsigned short* __restrict__ w116,
    unsigned short* __restrict__ w216) {
    const int t = threadIdx.x;
    int bid = blockIdx.x;
    if (bid < 3072) {
        const int i = bid * 256 + t;  // n4 = 786432
        float4 v = reinterpret_cast<const float4*>(x)[i];
        ushort4 o;
        o.x = f2b(v.x); o.y = f2b(v.y); o.z = f2b(v.z); o.w = f2b(v.w);
        reinterpret_cast<ushort4*>(x16)[i] = o;
        return;
    }
    bid -= 3072;
    const float* in; unsigned short* out; int R, C, bx, by;
    if (bid < 2304) {
        const int wsel = bid / 576, r = bid % 576;
        in = (wsel == 0) ? wq : (wsel == 1) ? wk : (wsel == 2) ? wv : wo;
        out = (wsel == 3) ? wo16 : wqkv16 + (size_t)wsel * DM * DM;
        R = DM; C = DM; bx = r % 24; by = r / 24;
    } else if (bid < 4608) {
        const int r = bid - 2304;
        in = w1; out = w116; R = DM; C = DFF; bx = r % 96; by = r / 96;
    } else {
        const int r = bid - 4608;
        in = w2; out = w216; R = DFF; C = DM; bx = r % 24; by = r / 24;
    }
    __shared__ float tile[32][33];
    const int c0 = bx * 32, r0 = by * 32;
    const int tx = t & 31, ty = t >> 5;
    #pragma unroll
    for (int i = ty; i < 32; i += 8)
        tile[i][tx] = in[(size_t)(r0 + i) * C + c0 + tx];
    __syncthreads();
    #pragma unroll
    for (int i = ty; i < 32; i += 8)
        out[(size_t)(c0 + i) * R + r0 + tx] = f2b(tile[tx][i]);
}

// ============ 256x192-tile GEMM, 8 waves, BK=64, dbuf LDS + counted vmcnt + T2 swizzle ============
// T1: XCD-chunked block remap. EPI 0: bf16+bias+relu. EPI 1: QKV head-split.
// EPI 3: bf16 split-K partials (via ob0). launch_bounds (512,2): no spills.
#define STG192(buf, kt)                                                                  \
    {                                                                                    \
        const char* ga = (const char*)(A + (size_t)bm * lda + koff + ((kt) << 6));       \
        const char* gb = (const char*)(Bt + (size_t)bn * ldb + koff + ((kt) << 6));      \
        char* la = (char*)Sh + (buf) * 57344 + t * 16;                                   \
        char* lb = (char*)Sh + (buf) * 57344 + 32768 + t * 16;                           \
        _Pragma("unroll")                                                                \
        for (int p = 0; p < 4; ++p)                                                      \
            gload16(ga + (size_t)(sr + p * 64) * la2 + scb_sw, la + p * 8192);           \
        _Pragma("unroll")                                                                \
        for (int p = 0; p < 3; ++p)                                                      \
            gload16(gb + (size_t)(sr + p * 64) * lb2 + scb_sw, lb + p * 8192);           \
    }

template <int EPI>
__global__ __launch_bounds__(512, 2) void gemm192(
    const unsigned short* __restrict__ A, int lda,
    const unsigned short* __restrict__ Bt, int ldb,
    const float* __restrict__ bias0, const float* __restrict__ bias1,
    const float* __restrict__ bias2,
    unsigned short* __restrict__ ob0, unsigned short* __restrict__ ob1,
    unsigned short* __restrict__ ob2, float* __restrict__ of,
    int M, int N, int Ksub, float qscale) {
    __shared__ __align__(16) unsigned short Sh[2 * 28672];  // 112 KB
    const int t = threadIdx.x;
    const int wave = t >> 6, lane = t & 63;
    const int wr = wave >> 2, wc = wave & 3;
    // T1 XCD-chunked remap on (x,y) linear id
    const int gx = gridDim.x;
    const int nl = gx * gridDim.y;
    const int lid = blockIdx.y * gx + blockIdx.x;
    const int logical = (lid & 7) * (nl >> 3) + (lid >> 3);
    const int bn = (logical % gx) * 192, bm = (logical / gx) * 256;
    const int koff = (EPI == 3) ? blockIdx.z * Ksub : 0;
    const int lr = lane & 15;
    const int lk8 = (lane >> 4) << 3;
    const int sr = t >> 3;
    const int scb = (t & 7) * 16;
    const int scb_sw = scb ^ ((sr & 7) << 4);  // pre-swizzled source column
    const int swr = (lr & 7) << 4;             // read-side XOR
    const size_t la2 = (size_t)lda * 2, lb2 = (size_t)ldb * 2;

    f32x4 acc[8][3];
    #pragma unroll
    for (int i = 0; i < 8; ++i)
        #pragma unroll
        for (int j = 0; j < 3; ++j) { f32x4 z = {0.f, 0.f, 0.f, 0.f}; acc[i][j] = z; }

    const int nkt = Ksub >> 6;
    STG192(0, 0)
    for (int kt = 0; kt < nkt; ++kt) {
        const int cur = kt & 1;
        if (kt + 1 < nkt) {
            STG192(cur ^ 1, kt + 1)
            asm volatile("s_waitcnt vmcnt(7)" ::: "memory");
        } else {
            asm volatile("s_waitcnt vmcnt(0)" ::: "memory");
        }
        __builtin_amdgcn_s_barrier();
        __builtin_amdgcn_sched_barrier(0);
        const char* Ab = (const char*)Sh + cur * 57344;
        const char* Bb = Ab + 32768;
        #pragma unroll
        for (int ks = 0; ks < 64; ks += 32) {
            const int cbsw = ((ks + lk8) * 2) ^ swr;
            bf16x8 af[8], bfv[3];
            #pragma unroll
            for (int i = 0; i < 8; ++i)
                af[i] = *reinterpret_cast<const bf16x8*>(Ab + (wr * 128 + i * 16 + lr) * 128 + cbsw);
            #pragma unroll
            for (int j = 0; j < 3; ++j)
                bfv[j] = *reinterpret_cast<const bf16x8*>(Bb + (wc * 48 + j * 16 + lr) * 128 + cbsw);
            __builtin_amdgcn_s_setprio(1);
            #pragma unroll
            for (int i = 0; i < 8; ++i)
                #pragma unroll
                for (int j = 0; j < 3; ++j)
                    acc[i][j] = __builtin_amdgcn_mfma_f32_16x16x32_bf16(af[i], bfv[j], acc[i][j], 0, 0, 0);
            __builtin_amdgcn_s_setprio(0);
        }
        __builtin_amdgcn_s_barrier();
    }

    const int r0 = (lane >> 4) << 2;
    if (EPI == 0) {
        #pragma unroll
        for (int i = 0; i < 8; ++i) {
            const int row_b = bm + wr * 128 + i * 16 + r0;
            #pragma unroll
            for (int j = 0; j < 3; ++j) {
                const int col = bn + wc * 48 + j * 16 + lr;
                const float bvv = bias0[col];
                #pragma unroll
                for (int r = 0; r < 4; ++r) {
                    float vv = acc[i][j][r] + bvv;
                    vv = vv > 0.f ? vv : 0.f;
                    ob0[(size_t)(row_b + r) * N + col] = f2b(vv);
                }
            }
        }
    } else if (EPI == 1) {
        const int sec = (bn >= 2 * DM) ? 2 : (bn >= DM ? 1 : 0);
        const int nb = bn - sec * DM;
        const float* bias = (sec == 0) ? bias0 : (sec == 1 ? bias1 : bias2);
        #pragma unroll
        for (int i = 0; i < 8; ++i) {
            const int row_b = bm + wr * 128 + i * 16 + r0;
            const int b = row_b >> 11, s = row_b & 2047;
            #pragma unroll
            for (int j = 0; j < 3; ++j) {
                const int c768 = nb + wc * 48 + j * 16 + lr;
                const int h = c768 >> 6, d = c768 & 63;
                const float bvv = bias[c768];
                if (sec == 2) {
                    ushort4 w;
                    w.x = f2b(acc[i][j][0] + bvv);
                    w.y = f2b(acc[i][j][1] + bvv);
                    w.z = f2b(acc[i][j][2] + bvv);
                    w.w = f2b(acc[i][j][3] + bvv);
                    *reinterpret_cast<ushort4*>(
                        ob2 + (((size_t)(b * NH + h) * DKH) + d) * S_LEN + s) = w;
                } else {
                    const float sc = (sec == 0) ? qscale : 1.f;
                    unsigned short* dst = (sec == 0) ? ob0 : ob1;
                    #pragma unroll
                    for (int r = 0; r < 4; ++r)
                        dst[(((size_t)(b * NH + h) * S_LEN) + s + r) * DKH + d] =
                            f2b((acc[i][j][r] + bvv) * sc);
                }
            }
        }
    } else {  // EPI == 3: bf16 split-K partials
        unsigned short* op = ob0 + (size_t)blockIdx.z * M * N;
        #pragma unroll
        for (int i = 0; i < 8; ++i) {
            const int row_b = bm + wr * 128 + i * 16 + r0;
            #pragma unroll
            for (int j = 0; j < 3; ++j) {
                const int col = bn + wc * 48 + j * 16 + lr;
                #pragma unroll
                for (int r = 0; r < 4; ++r)
                    op[(size_t)(row_b + r) * N + col] = f2b(acc[i][j][r]);
            }
        }
    }
}

// ---------------- MFMA causal flash attention: r16-measured best (KVBLK=64, 32KB dbuf) ----------------
#define STAGEKV(buf, kt)                                                              \
    {                                                                                 \
        const char* kg = kbyte + (((size_t)(kt)) << 13);                              \
        const char* vg = vbyte + (((size_t)(kt)) << 7);                               \
        char* lk = (char*)&KV[buf][0][0] + lane * 16;                                 \
        char* lv = (char*)&KV[buf][1][0] + lane * 16;                                 \
        _Pragma("unroll")                                                             \
        for (int i = 0; i < 8; ++i)                                                   \
            gload16(kg + (i * 8 + sub) * 128 + ccs, lk + i * 1024);                   \
        _Pragma("unroll")                                                             \
        for (int i = 0; i < 8; ++i)                                                   \
            gload16(vg + (size_t)(i * 8 + sub) * (S_LEN * 2) + ccs, lv + i * 1024);   \
    }

__global__ __launch_bounds__(64) void attn_mfma_kernel(
    const unsigned short* __restrict__ q16,   // [B,H,S,64]
    const unsigned short* __restrict__ k16,   // [B,H,S,64]
    const unsigned short* __restrict__ vt16,  // [B,H,64,S]
    unsigned short* __restrict__ ctx16) {     // [B,S,DM]
    __shared__ __align__(16) char KV[2][2][8192];  // [buf][K/V] 32 KB
    const int lane = threadIdx.x & 63;
    const int bh = blockIdx.x;
    const int qb = (gridDim.y - 1) - blockIdx.y;
    const int b = bh / NH, h = bh % NH;
    const size_t hbase = (size_t)bh * S_LEN * DKH;
    const int x = lane & 31;
    const int hi = lane >> 5;
    const int k8 = hi << 3;
    const int sW = qb << 5;
    const int qg = sW + x;
    const int sub = lane >> 3;
    const int ccs = ((lane & 7) * 16) ^ (sub << 4);
    const int swz = (x & 7) << 4;

    bf16x8 qa[4];
    #pragma unroll
    for (int c = 0; c < 4; ++c)
        qa[c] = *reinterpret_cast<const bf16x8*>(
            q16 + hbase + (size_t)(sW + x) * DKH + c * 16 + k8);

    float mst = -3e38f, lst = 0.f;
    f32x16 acc0, acc1;
    #pragma unroll
    for (int r = 0; r < 16; ++r) { acc0[r] = 0.f; acc1[r] = 0.f; }

    const char* kbyte = (const char*)(k16 + hbase);
    const char* vbyte = (const char*)(vt16 + hbase);
    const int nt = (sW >> 6) + 1;

    STAGEKV(0, 0)
    for (int kt = 0; kt < nt; ++kt) {
        const int cur = kt & 1;
        asm volatile("s_waitcnt vmcnt(0)" ::: "memory");
        if (kt + 1 < nt) STAGEKV(cur ^ 1, kt + 1)
        const char* Kb = (const char*)&KV[cur][0][0];
        const char* Vb = (const char*)&KV[cur][1][0];
        const int k0 = kt << 6;

        bf16x8 kaf[2][4];
        #pragma unroll
        for (int kh = 0; kh < 2; ++kh)
            #pragma unroll
            for (int c = 0; c < 4; ++c)
                kaf[kh][c] = *reinterpret_cast<const bf16x8*>(
                    Kb + (kh * 32 + x) * 128 + ((c * 32 + hi * 16) ^ swz));

        f32x16 sc0, sc1;
        #pragma unroll
        for (int r = 0; r < 16; ++r) { sc0[r] = 0.f; sc1[r] = 0.f; }
        __builtin_amdgcn_s_setprio(1);
        #pragma unroll
        for (int c = 0; c < 4; ++c) {
            sc0 = __builtin_amdgcn_mfma_f32_32x32x16_bf16(kaf[0][c], qa[c], sc0, 0, 0, 0);
            sc1 = __builtin_amdgcn_mfma_f32_32x32x16_bf16(kaf[1][c], qa[c], sc1, 0, 0, 0);
        }
        __builtin_amdgcn_s_setprio(0);

        if (kt == nt - 1) {
            #pragma unroll
            for (int r = 0; r < 16; ++r) {
                const int cr = (r & 3) + (hi << 2) + ((r >> 2) << 3);
                if (k0 + cr > qg) sc0[r] = -3e38f;
                if (k0 + 32 + cr > qg) sc1[r] = -3e38f;
            }
        }

        float tm = fmaxf(sc0[0], sc0[1]);
        #pragma unroll
        for (int r = 2; r < 16; ++r) tm = fmaxf(tm, sc0[r]);
        #pragma unroll
        for (int r = 0; r < 16; ++r) tm = fmaxf(tm, sc1[r]);
        tm = fmaxf(tm, __shfl_xor(tm, 32));

        if (!__all(tm <= mst + 8.f)) {
            const float mn = fmaxf(mst, tm);
            const float corr = exp2f(mst - mn);
            mst = mn;
            lst *= corr;
            float cw[16];
            #pragma unroll
            for (int r = 0; r < 16; ++r)
                cw[r] = __shfl(corr, (r & 3) + (hi << 2) + ((r >> 2) << 3));
            #pragma unroll
            for (int r = 0; r < 16; ++r) { acc0[r] *= cw[r]; acc1[r] *= cw[r]; }
        }

        float ts = 0.f;
        #pragma unroll
        for (int r = 0; r < 16; ++r) {
            sc0[r] = exp2f(sc0[r] - mst); ts += sc0[r];
            sc1[r] = exp2f(sc1[r] - mst); ts += sc1[r];
        }
        ts += __shfl_xor(ts, 32);
        lst += ts;

        unsigned a0 = cvtpk(sc0[0], sc0[1]),   b0 = cvtpk(sc0[4], sc0[5]);   pswap(a0, b0);
        unsigned a1 = cvtpk(sc0[2], sc0[3]),   b1 = cvtpk(sc0[6], sc0[7]);   pswap(a1, b1);
        unsigned a2 = cvtpk(sc0[8], sc0[9]),   b2 = cvtpk(sc0[12], sc0[13]); pswap(a2, b2);
        unsigned a3 = cvtpk(sc0[10], sc0[11]), b3 = cvtpk(sc0[14], sc0[15]); pswap(a3, b3);
        bf16x8 pa00 = mkpa(a0, a1, b0, b1);
        bf16x8 pa01 = mkpa(a2, a3, b2, b3);
        unsigned c0 = cvtpk(sc1[0], sc1[1]),   d0 = cvtpk(sc1[4], sc1[5]);   pswap(c0, d0);
        unsigned c1 = cvtpk(sc1[2], sc1[3]),   d1 = cvtpk(sc1[6], sc1[7]);   pswap(c1, d1);
        unsigned c2 = cvtpk(sc1[8], sc1[9]),   d2 = cvtpk(sc1[12], sc1[13]); pswap(c2, d2);
        unsigned c3 = cvtpk(sc1[10], sc1[11]), d3 = cvtpk(sc1[14], sc1[15]); pswap(c3, d3);
        bf16x8 pa10 = mkpa(c0, c1, d0, d1);
        bf16x8 pa11 = mkpa(c2, c3, d2, d3);

        bf16x8 vaf[2][4];
        #pragma unroll
        for (int dt = 0; dt < 2; ++dt)
            #pragma unroll
            for (int s = 0; s < 4; ++s)
                vaf[dt][s] = *reinterpret_cast<const bf16x8*>(
                    Vb + (dt * 32 + x) * 128 + ((s * 32 + hi * 16) ^ swz));

        __builtin_amdgcn_s_setprio(1);
        acc0 = __builtin_amdgcn_mfma_f32_32x32x16_bf16(pa00, vaf[0][0], acc0, 0, 0, 0);
        acc1 = __builtin_amdgcn_mfma_f32_32x32x16_bf16(pa00, vaf[1][0], acc1, 0, 0, 0);
        acc0 = __builtin_amdgcn_mfma_f32_32x32x16_bf16(pa01, vaf[0][1], acc0, 0, 0, 0);
        acc1 = __builtin_amdgcn_mfma_f32_32x32x16_bf16(pa01, vaf[1][1], acc1, 0, 0, 0);
        acc0 = __builtin_amdgcn_mfma_f32_32x32x16_bf16(pa10, vaf[0][2], acc0, 0, 0, 0);
        acc1 = __builtin_amdgcn_mfma_f32_32x32x16_bf16(pa10, vaf[1][2], acc1, 0, 0, 0);
        acc0 = __builtin_amdgcn_mfma_f32_32x32x16_bf16(pa11, vaf[0][3], acc0, 0, 0, 0);
        acc1 = __builtin_amdgcn_mfma_f32_32x32x16_bf16(pa11, vaf[1][3], acc1, 0, 0, 0);
        __builtin_amdgcn_s_setprio(0);
    }

    const float li = 1.f / lst;
    float lw[16];
    #pragma unroll
    for (int r = 0; r < 16; ++r)
        lw[r] = __shfl(li, (r & 3) + (hi << 2) + ((r >> 2) << 3));
    #pragma unroll
    for (int r = 0; r < 16; ++r) {
        const int q = sW + (r & 3) + (hi << 2) + ((r >> 2) << 3);
        const size_t rowb = ((size_t)b * S_LEN + q) * DM + h * DKH;
        ctx16[rowb + x] = f2b(acc0[r] * lw[r]);
        ctx16[rowb + 32 + x] = f2b(acc1[r] * lw[r]);
    }
}

// ---------------- fused bf16-split-K merge + LayerNorm (192 thr/row) ----------------
template <int EB16OUT, int RES16>
__global__ __launch_bounds__(192) void ln_merge_kernel(
    const unsigned short* __restrict__ part, size_t pstride, int ns,
    const void* __restrict__ res, const float* __restrict__ bias,
    const float* __restrict__ gam, const float* __restrict__ bet,
    float* __restrict__ outf, unsigned short* __restrict__ outb) {
    __shared__ float red[8];
    const int row = blockIdx.x, t = threadIdx.x;
    const int wave = t >> 6, lane = t & 63;
    const size_t base = (size_t)row * DM;
    float4 v;
    if (RES16) {
        const ushort4 rv = reinterpret_cast<const ushort4*>((const unsigned short*)res + base)[t];
        v.x = b2f(rv.x); v.y = b2f(rv.y); v.z = b2f(rv.z); v.w = b2f(rv.w);
    } else {
        v = reinterpret_cast<const float4*>((const float*)res + base)[t];
    }
    const float4 bv = reinterpret_cast<const float4*>(bias)[t];
    v.x += bv.x; v.y += bv.y; v.z += bv.z; v.w += bv.w;
    for (int z = 0; z < ns; ++z) {
        const ushort4 p = reinterpret_cast<const ushort4*>(part + (size_t)z * pstride + base)[t];
        v.x += b2f(p.x); v.y += b2f(p.y); v.z += b2f(p.z); v.w += b2f(p.w);
    }
    float s = v.x + v.y + v.z + v.w;
    float sq = v.x * v.x + v.y * v.y + v.z * v.z + v.w * v.w;
    #pragma unroll
    for (int off = 32; off > 0; off >>= 1) { s += __shfl_xor(s, off); sq += __shfl_xor(sq, off); }
    if (lane == 0) { red[wave] = s; red[wave + 4] = sq; }
    __syncthreads();
    s = red[0] + red[1] + red[2];
    sq = red[4] + red[5] + red[6];
    const float mu = s * (1.f / DM);
    const float var = sq * (1.f / DM) - mu * mu;
    const float rs = rsqrtf(var + 1e-5f);
    const float4 g = reinterpret_cast<const float4*>(gam)[t];
    const float4 be = reinterpret_cast<const float4*>(bet)[t];
    float4 o;
    o.x = (v.x - mu) * rs * g.x + be.x;
    o.y = (v.y - mu) * rs * g.y + be.y;
    o.z = (v.z - mu) * rs * g.z + be.z;
    o.w = (v.w - mu) * rs * g.w + be.w;
    if (EB16OUT) {
        ushort4 ob;
        ob.x = f2b(o.x); ob.y = f2b(o.y); ob.z = f2b(o.z); ob.w = f2b(o.w);
        reinterpret_cast<ushort4*>(outb + base)[t] = ob;
    } else {
        reinterpret_cast<float4*>(outf + base)[t] = o;
    }
}

extern "C" void kernel_launch(void* const* d_in, const int* in_sizes, int n_in,
                              void* d_out, int out_size, void* d_ws, size_t ws_size,
                              hipStream_t stream) {
    const float* x   = (const float*)d_in[0];
    const float* wq  = (const float*)d_in[1];
    const float* bq  = (const float*)d_in[2];
    const float* wk  = (const float*)d_in[3];
    const float* bk  = (const float*)d_in[4];
    const float* wv  = (const float*)d_in[5];
    const float* bv  = (const float*)d_in[6];
    const float* wo  = (const float*)d_in[7];
    const float* bo  = (const float*)d_in[8];
    const float* w1  = (const float*)d_in[9];
    const float* b1  = (const float*)d_in[10];
    const float* w2  = (const float*)d_in[11];
    const float* b2  = (const float*)d_in[12];
    const float* g1  = (const float*)d_in[13];
    const float* be1 = (const float*)d_in[14];
    const float* g2  = (const float*)d_in[15];
    const float* be2 = (const float*)d_in[16];

    char* wp = (char*)d_ws;
    auto alloc = [&](size_t bytes) -> void* {
        void* r = (void*)wp;
        wp += (bytes + 255) & ~(size_t)255;
        return r;
    };
    const int M = MROWS;
    unsigned short* wqkv16 = (unsigned short*)alloc((size_t)3 * DM * DM * 2);  // [2304][768]
    unsigned short* wo16 = (unsigned short*)alloc((size_t)DM * DM * 2);
    unsigned short* w116 = (unsigned short*)alloc((size_t)DM * DFF * 2);
    unsigned short* w216 = (unsigned short*)alloc((size_t)DM * DFF * 2);
    unsigned short* ctx16 = (unsigned short*)alloc((size_t)M * DM * 2);
    unsigned short* x16  = (unsigned short*)alloc((size_t)M * DM * 2);
    unsigned short* q16  = (unsigned short*)alloc((size_t)M * DM * 2);
    unsigned short* k16  = (unsigned short*)alloc((size_t)M * DM * 2);
    unsigned short* vt16 = (unsigned short*)alloc((size_t)M * DM * 2);
    unsigned short* ff116 = x16;    // [M,DFF] bf16 over x16..vt16 (dead after attn)
    unsigned short* x116  = ctx16;  // LN1 bf16 output (ctx16 dead after WO gemm); also LN2 residual

    const size_t perb = (size_t)M * DM * 2;  // bf16 partial slice
    size_t used = (size_t)(wp - (char*)d_ws);
    int NS = 1;
    if (used + 4 * perb + 1024 <= ws_size) NS = 4;
    else if (used + 2 * perb + 1024 <= ws_size) NS = 2;
    unsigned short* part = (unsigned short*)alloc((size_t)NS * perb);
    const int NSW = (NS >= 2) ? 2 : 1;  // WO split-K factor

    prep_kernel<<<9984, 256, 0, stream>>>(x, wq, wk, wv, wo, w1, w2,
                                          x16, wqkv16, wo16, w116, w216);

    const float QSCALE = 0.125f * 1.44269504088896f;
    // QKV: 256x192 tile, N=2304 -> 12x16 = 192 blocks
    gemm192<1><<<dim3(3 * DM / 192, M / 256), 512, 0, stream>>>(
        x16, DM, wqkv16, DM, bq, bk, bv, q16, k16, vt16, nullptr, M, 3 * DM, DM, QSCALE);

    attn_mfma_kernel<<<dim3(NBH, S_LEN / 32), 64, 0, stream>>>(q16, k16, vt16, ctx16);

    // WO proj: split-K=NSW bf16 partials; LN1 = LN(sum + bo + x) -> x116 (bf16)
    gemm192<3><<<dim3(DM / 192, M / 256, NSW), 512, 0, stream>>>(
        ctx16, DM, wo16, DM, nullptr, nullptr, nullptr, part, nullptr, nullptr, nullptr,
        M, DM, DM / NSW, 1.f);
    ln_merge_kernel<1, 0><<<M, 192, 0, stream>>>(part, (size_t)M * DM, NSW, x, bo, g1, be1,
                                                 nullptr, x116);

    // FFN1: N=3072 -> 16x16 = 256 blocks (100% fill)
    gemm192<0><<<dim3(DFF / 192, M / 256), 512, 0, stream>>>(
        x116, DM, w116, DM, b1, nullptr, nullptr, ff116, nullptr, nullptr, nullptr, M, DFF, DM, 1.f);

    // FFN2: split-K=NS bf16 partials; LN2 = LN(sum + b2 + x116) -> d_out (f32)
    gemm192<3><<<dim3(DM / 192, M / 256, NS), 512, 0, stream>>>(
        ff116, DFF, w216, DFF, nullptr, nullptr, nullptr, part, nullptr, nullptr, nullptr,
        M, DM, DFF / NS, 1.f);
    ln_merge_kernel<0, 1><<<M, 192, 0, stream>>>(part, (size_t)M * DM, NS, x116, b2, g2, be2,
                                                 (float*)d_out, nullptr);
}